// Round 7
// baseline (166.210 us; speedup 1.0000x reference)
//
#include <hip/hip_runtime.h>
#include <hip/hip_bf16.h>

// PhraseClassifier R17.
//   R16 post-mortem: proj conflicts 9x down + LDS-free epilogue -> dur FLAT
//   (42.6us). proj has now survived occupancy-2x / stage-coalescing /
//   B-pipeline / conflict-elimination all unchanged => bound externally
//   (harness poison-fill writeback drains through HBM/L3 during proj; fills
//   also evict hidden from L3 -> 37MB cold fetch). Stop touching proj.
//   span_eval: 41us, FETCH 20MB (L2-residency WORKS), VALUBusy 30% = top
//   measured pipe; ~117 VALU/span/lane, scalar combine dominates.
//   R17 (span only; proj = control):
//     - keep fp8 decode outputs PACKED (f32x2) and combine with packed math
//       (v_pk_add/max/fma via vector ops): 80 -> 40 combine ops/span.
//     - load pipeline depth 3 -> 4 (16 uint4 in flight; VGPR ~136, still
//       >= 3 waves/SIMD vs 1.4 measured avg).
//   Predict: span 41 -> 32-36us, FETCH unchanged; proj unchanged; total ~158.

typedef float f32x4 __attribute__((ext_vector_type(4)));
typedef float f32x2 __attribute__((ext_vector_type(2)));
typedef __bf16 bf16x8 __attribute__((ext_vector_type(8)));
typedef __bf16 bf16x4 __attribute__((ext_vector_type(4)));

__device__ __forceinline__ unsigned short f2bf(float f) {
  unsigned int u = __float_as_uint(f);
  u += 0x7fffu + ((u >> 16) & 1u);   // RNE
  return (unsigned short)(u >> 16);
}
__device__ __forceinline__ float bf2f(unsigned int lo16) {
  return __uint_as_float(lo16 << 16);
}

// ---- prep: W1 blocking (blocks 0..255) + span bid histogram (256..383) ----
__global__ void prep(const float* __restrict__ W1,
                     unsigned short* __restrict__ W1b,
                     const int* __restrict__ bids, int* __restrict__ ghist,
                     int nspans) {
  __shared__ int h[32];
  int t = threadIdx.x;
  if (blockIdx.x < 256) {
    int idx = blockIdx.x * 256 + t;             // 0..65535
    int kc = idx & 3;
    int n  = (idx >> 2) & 511;
    int c  = idx >> 11;
    int k0 = c * 32 + kc * 8;
    unsigned short tmp[8];
#pragma unroll
    for (int j = 0; j < 8; ++j)
      tmp[j] = f2bf(W1[(k0 + j) * 512 + n]);
    *(uint4*)(W1b + c * 16384 + n * 32 + kc * 8) = *(uint4*)tmp;
  } else {
    if (t < 32) h[t] = 0;
    __syncthreads();
    int base = (blockIdx.x - 256) * 1024;
#pragma unroll
    for (int i = 0; i < 4; ++i) {
      int idx = base + t + i * 256;
      if (idx < nspans) atomicAdd(&h[bids[idx]], 1);
    }
    __syncthreads();
    if (t < 32) atomicAdd(&ghist[t], h[t]);
  }
}

// ---- span scatter (counting sort by bid into sidx) ----
__global__ void span_scatter(const int* __restrict__ bids,
                             const int* __restrict__ ghist,
                             int* __restrict__ gslot,
                             int* __restrict__ sidx, int nspans) {
  __shared__ int lh[32], lbase[32], lcur[32];
  int t = threadIdx.x;
  if (t < 32) lh[t] = 0;
  __syncthreads();
  int base = blockIdx.x * 512;
  int myb[2];
#pragma unroll
  for (int i = 0; i < 2; ++i) {
    int idx = base + t + i * 256;
    myb[i] = (idx < nspans) ? bids[idx] : -1;
    if (myb[i] >= 0) atomicAdd(&lh[myb[i]], 1);
  }
  __syncthreads();
  if (t < 32) {
    int pre = 0;
    for (int j = 0; j < t; ++j) pre += ghist[j];   // exclusive prefix
    lbase[t] = pre + atomicAdd(&gslot[t], lh[t]);  // reserve chunk
    lcur[t] = 0;
  }
  __syncthreads();
#pragma unroll
  for (int i = 0; i < 2; ++i) {
    int b = myb[i];
    if (b >= 0) {
      int pos = lbase[b] + atomicAdd(&lcur[b], 1);
      sidx[pos] = base + t + i * 256;
    }
  }
}

// ---------------- proj_gemm v4 (unchanged from R16) ----------------
__global__ __launch_bounds__(512, 4) void proj_gemm(
    const float* __restrict__ hidden,        // [16384][1024]
    const unsigned short* __restrict__ w1b,  // blocked [32][512][32] bf16
    unsigned char* __restrict__ Wq) {        // [16384][1024] fp8, cols perm'd
  __shared__ __align__(16) unsigned short LB[32768];  // 64 KiB

  const int t = threadIdx.x;                 // 0..511
  const int lane = t & 63;
  const int w = t >> 6;                      // 0..7
  const int r0 = blockIdx.x << 6;
  const int hk = blockIdx.y << 9;            // 0 (U) or 512 (V)
  const int q = lane >> 4;                   // k-sub 0..3
  const int m = lane & 15;

  {
    const int kq = lane >> 4;                // 0..3
    const int sm = lane & 15;                // row-within-group
#pragma unroll
    for (int ii = 0; ii < 2; ++ii) {
      const int it = (w << 1) + ii;
#pragma unroll
      for (int mt = 0; mt < 4; ++mt) {
#pragma unroll
        for (int hh = 0; hh < 2; ++hh) {
          const int kk_ = (hh << 4) + (kq << 2);    // k within tile, 0..28
          const float* gp = hidden + ((r0 + (mt << 4) + sm) << 10)
                                   + hk + (it << 5) + kk_;
          float4 f = *(const float4*)gp;
          bf16x4 hv;
          hv[0] = (__bf16)f.x; hv[1] = (__bf16)f.y;
          hv[2] = (__bf16)f.z; hv[3] = (__bf16)f.w;
          const int qq = kk_ >> 3;                  // k-quad
          const int kkr = kk_ & 7;                  // 0 or 4
          *(bf16x4*)(LB + (((it << 2) + mt) << 9)
                        + (((qq << 4) + sm) << 3) + kkr) = hv;
        }
      }
    }
  }
  __syncthreads();

  int boffn[4];
#pragma unroll
  for (int nt = 0; nt < 4; ++nt)
    boffn[nt] = (((w << 6) + (nt << 4) + m) << 5) + (q << 3);
  const unsigned short* w1base = w1b + (blockIdx.y << 18);

  f32x4 acc[4][4];
#pragma unroll
  for (int i = 0; i < 4; ++i)
#pragma unroll
    for (int j = 0; j < 4; ++j) acc[i][j] = (f32x4){0.f, 0.f, 0.f, 0.f};

#pragma unroll
  for (int it = 0; it < 16; ++it) {
    const unsigned short* bt = w1base + (it << 14);   // tile it
    bf16x8 bfr[4];
#pragma unroll
    for (int nt = 0; nt < 4; ++nt)
      bfr[nt] = *(const bf16x8*)(bt + boffn[nt]);
    bf16x8 af[4];
#pragma unroll
    for (int mt = 0; mt < 4; ++mt)
      af[mt] = *(const bf16x8*)(LB + (((it << 2) + mt) << 9)
                                   + (((q << 4) + m) << 3));
#pragma unroll
    for (int mt = 0; mt < 4; ++mt)
#pragma unroll
      for (int nt = 0; nt < 4; ++nt)
        acc[mt][nt] = __builtin_amdgcn_mfma_f32_16x16x32_bf16(af[mt], bfr[nt],
                                                              acc[mt][nt], 0, 0, 0);
  }

  // ---- epilogue: LDS-free packed-fp8 dword stores, cols perm'd by sigma ----
  {
    const int cb = (w << 6) + (m << 2);
#pragma unroll
    for (int mt = 0; mt < 4; ++mt) {
#pragma unroll
      for (int r = 0; r < 4; ++r) {
        unsigned int o = __builtin_amdgcn_cvt_pk_fp8_f32(
            acc[mt][0][r], acc[mt][1][r], 0, false);
        o = __builtin_amdgcn_cvt_pk_fp8_f32(
            acc[mt][2][r], acc[mt][3][r], o, true);
        int grow = r0 + (mt << 4) + (q << 2) + r;
        if (hk == 0) {
          *(unsigned int*)(Wq + (grow << 10) + cb) = o;              // U[r]
        } else if (grow >= 32) {
          *(unsigned int*)(Wq + ((grow - 32) << 10) + 512 + cb) = o; // V
        }
      }
    }
  }
}

// ---------------- span_eval: packed f32x2 math, depth-4 pipeline ----------
#define SPB 64
__global__ __launch_bounds__(256) void span_eval(
    const unsigned char* __restrict__ Wq,
    const int* __restrict__ sidx,
    const int* __restrict__ bids, const int* __restrict__ begins,
    const int* __restrict__ ends, const int* __restrict__ flags,
    const float* __restrict__ weights,
    const float* __restrict__ b1, const float* __restrict__ w2,
    const float* __restrict__ b2, float* __restrict__ partials) {
  __shared__ int oB[SPB], oE[SPB], sfl[SPB];
  __shared__ float swt[SPB];
  __shared__ float red[4][3];
  const int t = threadIdx.x;
  const int lane = t & 63;
  const int w = t >> 6;
  const int h = lane >> 5;          // half-wave
  const int hl = lane & 31;

  // XCD swizzle: each XCD gets a contiguous chunk of bid-sorted spans.
  const int nblk = gridDim.x;
  int lb = blockIdx.x;
  if ((nblk & 7) == 0) {
    const int cpx = nblk >> 3;
    lb = (blockIdx.x & 7) * cpx + (blockIdx.x >> 3);
  }
  const int sbase = lb * SPB;

  if (t < SPB) {
    int s = sidx[sbase + t];
    int b = bids[s], bg = begins[s], en = ends[s];
    oB[t] = (((bg - 1) << 5) + b) << 10;   // row b-1: [U[b-1] | V[b]]
    oE[t] = (((en - 1) << 5) + b) << 10;   // row e-1: [U[e-1] | V[e]]
    sfl[t] = flags[s];
    swt[t] = weights[s];
  }
  __syncthreads();

  const int sp0 = ((w << 1) + h) << 3;   // my half-wave's first span (block-local)
  const int c0 = hl << 4;                // 16 bytes per lane
  // b1/w2 gathered through sigma into f32x2 pairs (pair i = bytes 2i,2i+1):
  // byte pos p = c0+j -> col (hl>>2)*64 + (j&3)*16 + (hl&3)*4 + (j>>2)
  f32x2 b1p[8], w2p[8];
#pragma unroll
  for (int i = 0; i < 8; ++i) {
#pragma unroll
    for (int j2 = 0; j2 < 2; ++j2) {
      int j = 2 * i + j2;
      int colp = ((hl >> 2) << 6) + ((j & 3) << 4) + ((hl & 3) << 2) + (j >> 2);
      b1p[i][j2] = b1[colp];
      w2p[i][j2] = w2[colp];
    }
  }

  auto dec2 = [](unsigned int v, f32x2* f) {
    f[0] = __builtin_amdgcn_cvt_pk_f32_fp8(v, false);   // bytes 0,1
    f[1] = __builtin_amdgcn_cvt_pk_f32_fp8(v, true);    // bytes 2,3
  };

  uint4 BU[4], BV[4], EU[4], EV[4];
  auto ld = [&](int slot, int j) {
    int ob = oB[sp0 + j], oe = oE[sp0 + j];
    BU[slot] = *(const uint4*)(Wq + ob + c0);        // U[b-1] chunk
    BV[slot] = *(const uint4*)(Wq + ob + 512 + c0);  // V[b]   chunk
    EU[slot] = *(const uint4*)(Wq + oe + c0);        // U[e-1] chunk
    EV[slot] = *(const uint4*)(Wq + oe + 512 + c0);  // V[e]   chunk
  };
  ld(0, 0); ld(1, 1); ld(2, 2); ld(3, 3);

  const f32x2 zero2 = (f32x2){0.f, 0.f};
  float mylogit = 0.f;
#pragma unroll
  for (int j = 0; j < 8; ++j) {
    const int slot = j & 3;
    f32x2 bu2[8], bv2[8], eu2[8], ev2[8];
    dec2(BU[slot].x, bu2 + 0); dec2(BU[slot].y, bu2 + 2);
    dec2(BU[slot].z, bu2 + 4); dec2(BU[slot].w, bu2 + 6);
    dec2(BV[slot].x, bv2 + 0); dec2(BV[slot].y, bv2 + 2);
    dec2(BV[slot].z, bv2 + 4); dec2(BV[slot].w, bv2 + 6);
    dec2(EU[slot].x, eu2 + 0); dec2(EU[slot].y, eu2 + 2);
    dec2(EU[slot].z, eu2 + 4); dec2(EU[slot].w, eu2 + 6);
    dec2(EV[slot].x, ev2 + 0); dec2(EV[slot].y, ev2 + 2);
    dec2(EV[slot].z, ev2 + 4); dec2(EV[slot].w, ev2 + 6);
    if (j + 4 < 8) ld(slot, j + 4);
    f32x2 sv2 = zero2;
#pragma unroll
    for (int i = 0; i < 8; ++i) {
      f32x2 zp = eu2[i] - bu2[i] + bv2[i] - ev2[i] + b1p[i];
      zp = __builtin_elementwise_max(zp, zero2);
      sv2 = sv2 + zp * w2p[i];
    }
    float sv = sv2[0] + sv2[1];
    sv += __shfl_xor(sv, 1);
    sv += __shfl_xor(sv, 2);
    sv += __shfl_xor(sv, 4);
    sv += __shfl_xor(sv, 8);
    sv += __shfl_xor(sv, 16);       // reduce within half-wave
    if (hl == j) mylogit = sv;      // lane h*32+j parks span sp0+j
  }

  // span w*16+l (l<16) parked at lane ((l&8)<<2)+(l&7)
  mylogit = __shfl(mylogit, ((lane & 8) << 2) + (lane & 7));

  float pos_t = 0.f, neg_t = 0.f, cnt_t = 0.f;
  if (lane < 16) {
    int sl = (w << 4) + lane;       // block-local span id
    float logit = mylogit + b2[0];
    float p = 1.f / (1.f + expf(-logit));
    p = fminf(fmaxf(p, 1e-7f), 1.f - 1e-7f);
    int fl = sfl[sl];
    float bce = (fl == 1) ? -logf(p) : -logf(1.f - p);
    float term = swt[sl] * bce;
    pos_t = (fl == 1) ? term : 0.f;
    neg_t = (fl == 1) ? 0.f : term;
    cnt_t = (fl == 1) ? 1.f : 0.f;
  }
#pragma unroll
  for (int off = 1; off < 64; off <<= 1) {
    pos_t += __shfl_xor(pos_t, off);
    neg_t += __shfl_xor(neg_t, off);
    cnt_t += __shfl_xor(cnt_t, off);
  }
  if (lane == 0) { red[w][0] = pos_t; red[w][1] = neg_t; red[w][2] = cnt_t; }
  __syncthreads();
  if (t == 0) {
    partials[(blockIdx.x << 2) + 0] = red[0][0] + red[1][0] + red[2][0] + red[3][0];
    partials[(blockIdx.x << 2) + 1] = red[0][1] + red[1][1] + red[2][1] + red[3][1];
    partials[(blockIdx.x << 2) + 2] = red[0][2] + red[1][2] + red[2][2] + red[3][2];
  }
}

// ---------------- finalize ----------------
__global__ void finalize(const float* __restrict__ parts, int nblk,
                         float* __restrict__ out, int nspans) {
  __shared__ float sp[4], sn[4], sc[4];
  float P = 0.f, Ng = 0.f, C = 0.f;
  for (int i = threadIdx.x; i < nblk; i += 256) {
    P += parts[(i << 2) + 0];
    Ng += parts[(i << 2) + 1];
    C += parts[(i << 2) + 2];
  }
#pragma unroll
  for (int off = 1; off < 64; off <<= 1) {
    P += __shfl_xor(P, off);
    Ng += __shfl_xor(Ng, off);
    C += __shfl_xor(C, off);
  }
  int w = threadIdx.x >> 6;
  if ((threadIdx.x & 63) == 0) { sp[w] = P; sn[w] = Ng; sc[w] = C; }
  __syncthreads();
  if (threadIdx.x == 0) {
    P = sp[0] + sp[1] + sp[2] + sp[3];
    Ng = sn[0] + sn[1] + sn[2] + sn[3];
    C = sc[0] + sc[1] + sc[2] + sc[3];
    float scale = 2.f * C / (float)nspans;
    out[0] = (P + scale * Ng) / (float)nspans;
  }
}

extern "C" void kernel_launch(void* const* d_in, const int* in_sizes, int n_in,
                              void* d_out, int out_size, void* d_ws, size_t ws_size,
                              hipStream_t stream) {
  const float* hidden = (const float*)d_in[0];
  const int* bids     = (const int*)d_in[1];
  const int* begins   = (const int*)d_in[2];
  const int* ends     = (const int*)d_in[3];
  const int* flags    = (const int*)d_in[4];
  const float* weights = (const float*)d_in[5];
  const float* W1 = (const float*)d_in[6];
  const float* b1 = (const float*)d_in[7];
  const float* W2 = (const float*)d_in[8];
  const float* b2 = (const float*)d_in[9];
  float* out = (float*)d_out;
  const int nspans = in_sizes[1];       // 131072
  const int nblk = nspans / SPB;        // 2048

  float* partials = (float*)d_ws;                                    // 32 KiB
  unsigned short* W1b = (unsigned short*)((char*)d_ws + (1 << 18));  // 1 MiB blocked
  unsigned char* Wq = (unsigned char*)((char*)d_ws + (2 << 20));     // 16.8 MiB
  int* ghist = (int*)((char*)d_ws + (19 << 20));                     // 32 ints
  int* gslot = ghist + 32;                                           // 32 ints
  int* sidx  = (int*)((char*)d_ws + (20 << 20));                     // 512 KiB

  hipMemsetAsync(ghist, 0, 64 * sizeof(int), stream);
  prep<<<384, 256, 0, stream>>>(W1, W1b, bids, ghist, nspans);
  span_scatter<<<(nspans + 511) / 512, 256, 0, stream>>>(bids, ghist, gslot,
                                                         sidx, nspans);
  proj_gemm<<<dim3(256, 2), 512, 0, stream>>>(hidden, W1b, Wq);
  span_eval<<<nblk, 256, 0, stream>>>(Wq, sidx, bids, begins, ends, flags,
                                      weights, b1, W2, b2, partials);
  finalize<<<1, 256, 0, stream>>>(partials, nblk, out, nspans);
}

// Round 8
// 162.986 us; speedup vs baseline: 1.0198x; 1.0198x over previous
//
#include <hip/hip_runtime.h>
#include <hip/hip_bf16.h>

// PhraseClassifier R18.
//   R17 post-mortem: packed math + depth-4 -> total IDENTICAL. VALU theory
//   dead. Facts: span 268MB @ 6.7TB/s from L2/L3, FETCH 20MB (sort works),
//   Occupancy 18% (=5.8 waves/CU) with 8192 waves available -> latency-bound
//   with too few waves in flight. Structure suspects: 2048 tiny blocks
//   (4 waves, ~130KB L2 reads each), per-block meta barrier + reduce tail,
//   pipeline drains every 8 spans.
//   R18 (span only; proj untouched control): grid 512, each block loops 4
//   chunks of 64 spans; meta double-buffered in LDS and loaded OVERLAPPED
//   with the previous chunk's data pipeline; b1/w2 sigma-gather amortized
//   4x; BCE tail accumulated in regs, block reduce ONCE.
//   Predict: span 40 -> 25-30us + occupancy up (occupancy-bound) OR flat
//   (L3-service floor -> pivot to bid-major Wq). proj/FETCH are controls.

typedef float f32x4 __attribute__((ext_vector_type(4)));
typedef float f32x2 __attribute__((ext_vector_type(2)));
typedef __bf16 bf16x8 __attribute__((ext_vector_type(8)));
typedef __bf16 bf16x4 __attribute__((ext_vector_type(4)));

__device__ __forceinline__ unsigned short f2bf(float f) {
  unsigned int u = __float_as_uint(f);
  u += 0x7fffu + ((u >> 16) & 1u);   // RNE
  return (unsigned short)(u >> 16);
}
__device__ __forceinline__ float bf2f(unsigned int lo16) {
  return __uint_as_float(lo16 << 16);
}

// ---- prep: W1 blocking (blocks 0..255) + span bid histogram (256..383) ----
__global__ void prep(const float* __restrict__ W1,
                     unsigned short* __restrict__ W1b,
                     const int* __restrict__ bids, int* __restrict__ ghist,
                     int nspans) {
  __shared__ int h[32];
  int t = threadIdx.x;
  if (blockIdx.x < 256) {
    int idx = blockIdx.x * 256 + t;             // 0..65535
    int kc = idx & 3;
    int n  = (idx >> 2) & 511;
    int c  = idx >> 11;
    int k0 = c * 32 + kc * 8;
    unsigned short tmp[8];
#pragma unroll
    for (int j = 0; j < 8; ++j)
      tmp[j] = f2bf(W1[(k0 + j) * 512 + n]);
    *(uint4*)(W1b + c * 16384 + n * 32 + kc * 8) = *(uint4*)tmp;
  } else {
    if (t < 32) h[t] = 0;
    __syncthreads();
    int base = (blockIdx.x - 256) * 1024;
#pragma unroll
    for (int i = 0; i < 4; ++i) {
      int idx = base + t + i * 256;
      if (idx < nspans) atomicAdd(&h[bids[idx]], 1);
    }
    __syncthreads();
    if (t < 32) atomicAdd(&ghist[t], h[t]);
  }
}

// ---- span scatter (counting sort by bid into sidx) ----
__global__ void span_scatter(const int* __restrict__ bids,
                             const int* __restrict__ ghist,
                             int* __restrict__ gslot,
                             int* __restrict__ sidx, int nspans) {
  __shared__ int lh[32], lbase[32], lcur[32];
  int t = threadIdx.x;
  if (t < 32) lh[t] = 0;
  __syncthreads();
  int base = blockIdx.x * 512;
  int myb[2];
#pragma unroll
  for (int i = 0; i < 2; ++i) {
    int idx = base + t + i * 256;
    myb[i] = (idx < nspans) ? bids[idx] : -1;
    if (myb[i] >= 0) atomicAdd(&lh[myb[i]], 1);
  }
  __syncthreads();
  if (t < 32) {
    int pre = 0;
    for (int j = 0; j < t; ++j) pre += ghist[j];   // exclusive prefix
    lbase[t] = pre + atomicAdd(&gslot[t], lh[t]);  // reserve chunk
    lcur[t] = 0;
  }
  __syncthreads();
#pragma unroll
  for (int i = 0; i < 2; ++i) {
    int b = myb[i];
    if (b >= 0) {
      int pos = lbase[b] + atomicAdd(&lcur[b], 1);
      sidx[pos] = base + t + i * 256;
    }
  }
}

// ---------------- proj_gemm v4 (unchanged from R16) ----------------
__global__ __launch_bounds__(512, 4) void proj_gemm(
    const float* __restrict__ hidden,        // [16384][1024]
    const unsigned short* __restrict__ w1b,  // blocked [32][512][32] bf16
    unsigned char* __restrict__ Wq) {        // [16384][1024] fp8, cols perm'd
  __shared__ __align__(16) unsigned short LB[32768];  // 64 KiB

  const int t = threadIdx.x;                 // 0..511
  const int lane = t & 63;
  const int w = t >> 6;                      // 0..7
  const int r0 = blockIdx.x << 6;
  const int hk = blockIdx.y << 9;            // 0 (U) or 512 (V)
  const int q = lane >> 4;                   // k-sub 0..3
  const int m = lane & 15;

  {
    const int kq = lane >> 4;                // 0..3
    const int sm = lane & 15;                // row-within-group
#pragma unroll
    for (int ii = 0; ii < 2; ++ii) {
      const int it = (w << 1) + ii;
#pragma unroll
      for (int mt = 0; mt < 4; ++mt) {
#pragma unroll
        for (int hh = 0; hh < 2; ++hh) {
          const int kk_ = (hh << 4) + (kq << 2);    // k within tile, 0..28
          const float* gp = hidden + ((r0 + (mt << 4) + sm) << 10)
                                   + hk + (it << 5) + kk_;
          float4 f = *(const float4*)gp;
          bf16x4 hv;
          hv[0] = (__bf16)f.x; hv[1] = (__bf16)f.y;
          hv[2] = (__bf16)f.z; hv[3] = (__bf16)f.w;
          const int qq = kk_ >> 3;                  // k-quad
          const int kkr = kk_ & 7;                  // 0 or 4
          *(bf16x4*)(LB + (((it << 2) + mt) << 9)
                        + (((qq << 4) + sm) << 3) + kkr) = hv;
        }
      }
    }
  }
  __syncthreads();

  int boffn[4];
#pragma unroll
  for (int nt = 0; nt < 4; ++nt)
    boffn[nt] = (((w << 6) + (nt << 4) + m) << 5) + (q << 3);
  const unsigned short* w1base = w1b + (blockIdx.y << 18);

  f32x4 acc[4][4];
#pragma unroll
  for (int i = 0; i < 4; ++i)
#pragma unroll
    for (int j = 0; j < 4; ++j) acc[i][j] = (f32x4){0.f, 0.f, 0.f, 0.f};

#pragma unroll
  for (int it = 0; it < 16; ++it) {
    const unsigned short* bt = w1base + (it << 14);   // tile it
    bf16x8 bfr[4];
#pragma unroll
    for (int nt = 0; nt < 4; ++nt)
      bfr[nt] = *(const bf16x8*)(bt + boffn[nt]);
    bf16x8 af[4];
#pragma unroll
    for (int mt = 0; mt < 4; ++mt)
      af[mt] = *(const bf16x8*)(LB + (((it << 2) + mt) << 9)
                                   + (((q << 4) + m) << 3));
#pragma unroll
    for (int mt = 0; mt < 4; ++mt)
#pragma unroll
      for (int nt = 0; nt < 4; ++nt)
        acc[mt][nt] = __builtin_amdgcn_mfma_f32_16x16x32_bf16(af[mt], bfr[nt],
                                                              acc[mt][nt], 0, 0, 0);
  }

  // ---- epilogue: LDS-free packed-fp8 dword stores, cols perm'd by sigma ----
  {
    const int cb = (w << 6) + (m << 2);
#pragma unroll
    for (int mt = 0; mt < 4; ++mt) {
#pragma unroll
      for (int r = 0; r < 4; ++r) {
        unsigned int o = __builtin_amdgcn_cvt_pk_fp8_f32(
            acc[mt][0][r], acc[mt][1][r], 0, false);
        o = __builtin_amdgcn_cvt_pk_fp8_f32(
            acc[mt][2][r], acc[mt][3][r], o, true);
        int grow = r0 + (mt << 4) + (q << 2) + r;
        if (hk == 0) {
          *(unsigned int*)(Wq + (grow << 10) + cb) = o;              // U[r]
        } else if (grow >= 32) {
          *(unsigned int*)(Wq + ((grow - 32) << 10) + 512 + cb) = o; // V
        }
      }
    }
  }
}

// ---------------- span_eval v2: 512 blocks x 4 chunks of 64 spans ----------
#define SPB 64
#define CHUNKS 4
__global__ __launch_bounds__(256) void span_eval(
    const unsigned char* __restrict__ Wq,
    const int* __restrict__ sidx,
    const int* __restrict__ bids, const int* __restrict__ begins,
    const int* __restrict__ ends, const int* __restrict__ flags,
    const float* __restrict__ weights,
    const float* __restrict__ b1, const float* __restrict__ w2,
    const float* __restrict__ b2, float* __restrict__ partials) {
  __shared__ int oB[2][SPB], oE[2][SPB], sfl[2][SPB];
  __shared__ float swt[2][SPB];
  __shared__ float red[4][3];
  const int t = threadIdx.x;
  const int lane = t & 63;
  const int w = t >> 6;
  const int h = lane >> 5;          // half-wave
  const int hl = lane & 31;

  // XCD swizzle over 512 blocks: each XCD gets a contiguous 64-block chunk
  // of the bid-sorted span order (~4 bids = 2MB slab per L2).
  const int nblk = gridDim.x;
  int lb = blockIdx.x;
  if ((nblk & 7) == 0) {
    const int cpx = nblk >> 3;
    lb = (blockIdx.x & 7) * cpx + (blockIdx.x >> 3);
  }
  const int base0 = lb * (SPB * CHUNKS);

  auto ldmeta = [&](int c) {
    if (t < SPB) {
      int s = sidx[base0 + c * SPB + t];
      int b = bids[s], bg = begins[s], en = ends[s];
      int p = c & 1;
      oB[p][t] = (((bg - 1) << 5) + b) << 10;   // row b-1: [U[b-1] | V[b]]
      oE[p][t] = (((en - 1) << 5) + b) << 10;   // row e-1: [U[e-1] | V[e]]
      sfl[p][t] = flags[s];
      swt[p][t] = weights[s];
    }
  };
  ldmeta(0);

  const int sp0 = ((w << 1) + h) << 3;   // my half-wave's first span (chunk-local)
  const int c0 = hl << 4;                // 16 bytes per lane
  // b1/w2 gathered through sigma into f32x2 pairs (once per block):
  // byte pos p = c0+j -> col (hl>>2)*64 + (j&3)*16 + (hl&3)*4 + (j>>2)
  f32x2 b1p[8], w2p[8];
#pragma unroll
  for (int i = 0; i < 8; ++i) {
#pragma unroll
    for (int j2 = 0; j2 < 2; ++j2) {
      int j = 2 * i + j2;
      int colp = ((hl >> 2) << 6) + ((j & 3) << 4) + ((hl & 3) << 2) + (j >> 2);
      b1p[i][j2] = b1[colp];
      w2p[i][j2] = w2[colp];
    }
  }
  const float b2v = b2[0];
  __syncthreads();                       // meta(0) visible

  auto dec2 = [](unsigned int v, f32x2* f) {
    f[0] = __builtin_amdgcn_cvt_pk_f32_fp8(v, false);   // bytes 0,1
    f[1] = __builtin_amdgcn_cvt_pk_f32_fp8(v, true);    // bytes 2,3
  };

  const f32x2 zero2 = (f32x2){0.f, 0.f};
  float pos_t = 0.f, neg_t = 0.f, cnt_t = 0.f;

  for (int c = 0; c < CHUNKS; ++c) {
    const int cur = c & 1;
    uint4 BU[4], BV[4], EU[4], EV[4];
    auto ld = [&](int slot, int j) {
      int ob = oB[cur][sp0 + j], oe = oE[cur][sp0 + j];
      BU[slot] = *(const uint4*)(Wq + ob + c0);        // U[b-1] chunk
      BV[slot] = *(const uint4*)(Wq + ob + 512 + c0);  // V[b]   chunk
      EU[slot] = *(const uint4*)(Wq + oe + c0);        // U[e-1] chunk
      EV[slot] = *(const uint4*)(Wq + oe + 512 + c0);  // V[e]   chunk
    };
    ld(0, 0); ld(1, 1); ld(2, 2); ld(3, 3);
    if (c + 1 < CHUNKS) ldmeta(c + 1);   // overlapped with data pipeline

    float mylogit = 0.f;
#pragma unroll
    for (int j = 0; j < 8; ++j) {
      const int slot = j & 3;
      f32x2 bu2[8], bv2[8], eu2[8], ev2[8];
      dec2(BU[slot].x, bu2 + 0); dec2(BU[slot].y, bu2 + 2);
      dec2(BU[slot].z, bu2 + 4); dec2(BU[slot].w, bu2 + 6);
      dec2(BV[slot].x, bv2 + 0); dec2(BV[slot].y, bv2 + 2);
      dec2(BV[slot].z, bv2 + 4); dec2(BV[slot].w, bv2 + 6);
      dec2(EU[slot].x, eu2 + 0); dec2(EU[slot].y, eu2 + 2);
      dec2(EU[slot].z, eu2 + 4); dec2(EU[slot].w, eu2 + 6);
      dec2(EV[slot].x, ev2 + 0); dec2(EV[slot].y, ev2 + 2);
      dec2(EV[slot].z, ev2 + 4); dec2(EV[slot].w, ev2 + 6);
      if (j + 4 < 8) ld(slot, j + 4);
      f32x2 sv2 = zero2;
#pragma unroll
      for (int i = 0; i < 8; ++i) {
        f32x2 zp = eu2[i] - bu2[i] + bv2[i] - ev2[i] + b1p[i];
        zp = __builtin_elementwise_max(zp, zero2);
        sv2 = sv2 + zp * w2p[i];
      }
      float sv = sv2[0] + sv2[1];
      sv += __shfl_xor(sv, 1);
      sv += __shfl_xor(sv, 2);
      sv += __shfl_xor(sv, 4);
      sv += __shfl_xor(sv, 8);
      sv += __shfl_xor(sv, 16);       // reduce within half-wave
      if (hl == j) mylogit = sv;      // lane h*32+j parks span sp0+j
    }

    // span w*16+l (l<16) parked at lane ((l&8)<<2)+(l&7)
    mylogit = __shfl(mylogit, ((lane & 8) << 2) + (lane & 7));

    if (lane < 16) {
      int sl = (w << 4) + lane;       // chunk-local span id
      float logit = mylogit + b2v;
      float p = 1.f / (1.f + expf(-logit));
      p = fminf(fmaxf(p, 1e-7f), 1.f - 1e-7f);
      int fl = sfl[cur][sl];
      float bce = (fl == 1) ? -logf(p) : -logf(1.f - p);
      float term = swt[cur][sl] * bce;
      pos_t += (fl == 1) ? term : 0.f;
      neg_t += (fl == 1) ? 0.f : term;
      cnt_t += (fl == 1) ? 1.f : 0.f;
    }
    __syncthreads();   // everyone done with meta[cur]; meta[cur^1] visible
  }

#pragma unroll
  for (int off = 1; off < 64; off <<= 1) {
    pos_t += __shfl_xor(pos_t, off);
    neg_t += __shfl_xor(neg_t, off);
    cnt_t += __shfl_xor(cnt_t, off);
  }
  if (lane == 0) { red[w][0] = pos_t; red[w][1] = neg_t; red[w][2] = cnt_t; }
  __syncthreads();
  if (t == 0) {
    partials[(blockIdx.x << 2) + 0] = red[0][0] + red[1][0] + red[2][0] + red[3][0];
    partials[(blockIdx.x << 2) + 1] = red[0][1] + red[1][1] + red[2][1] + red[3][1];
    partials[(blockIdx.x << 2) + 2] = red[0][2] + red[1][2] + red[2][2] + red[3][2];
  }
}

// ---------------- finalize ----------------
__global__ void finalize(const float* __restrict__ parts, int nblk,
                         float* __restrict__ out, int nspans) {
  __shared__ float sp[4], sn[4], sc[4];
  float P = 0.f, Ng = 0.f, C = 0.f;
  for (int i = threadIdx.x; i < nblk; i += 256) {
    P += parts[(i << 2) + 0];
    Ng += parts[(i << 2) + 1];
    C += parts[(i << 2) + 2];
  }
#pragma unroll
  for (int off = 1; off < 64; off <<= 1) {
    P += __shfl_xor(P, off);
    Ng += __shfl_xor(Ng, off);
    C += __shfl_xor(C, off);
  }
  int w = threadIdx.x >> 6;
  if ((threadIdx.x & 63) == 0) { sp[w] = P; sn[w] = Ng; sc[w] = C; }
  __syncthreads();
  if (threadIdx.x == 0) {
    P = sp[0] + sp[1] + sp[2] + sp[3];
    Ng = sn[0] + sn[1] + sn[2] + sn[3];
    C = sc[0] + sc[1] + sc[2] + sc[3];
    float scale = 2.f * C / (float)nspans;
    out[0] = (P + scale * Ng) / (float)nspans;
  }
}

extern "C" void kernel_launch(void* const* d_in, const int* in_sizes, int n_in,
                              void* d_out, int out_size, void* d_ws, size_t ws_size,
                              hipStream_t stream) {
  const float* hidden = (const float*)d_in[0];
  const int* bids     = (const int*)d_in[1];
  const int* begins   = (const int*)d_in[2];
  const int* ends     = (const int*)d_in[3];
  const int* flags    = (const int*)d_in[4];
  const float* weights = (const float*)d_in[5];
  const float* W1 = (const float*)d_in[6];
  const float* b1 = (const float*)d_in[7];
  const float* W2 = (const float*)d_in[8];
  const float* b2 = (const float*)d_in[9];
  float* out = (float*)d_out;
  const int nspans = in_sizes[1];       // 131072
  const int nblk = nspans / (SPB * CHUNKS);   // 512

  float* partials = (float*)d_ws;                                    // 32 KiB
  unsigned short* W1b = (unsigned short*)((char*)d_ws + (1 << 18));  // 1 MiB blocked
  unsigned char* Wq = (unsigned char*)((char*)d_ws + (2 << 20));     // 16.8 MiB
  int* ghist = (int*)((char*)d_ws + (19 << 20));                     // 32 ints
  int* gslot = ghist + 32;                                           // 32 ints
  int* sidx  = (int*)((char*)d_ws + (20 << 20));                     // 512 KiB

  hipMemsetAsync(ghist, 0, 64 * sizeof(int), stream);
  prep<<<384, 256, 0, stream>>>(W1, W1b, bids, ghist, nspans);
  span_scatter<<<(nspans + 511) / 512, 256, 0, stream>>>(bids, ghist, gslot,
                                                         sidx, nspans);
  proj_gemm<<<dim3(256, 2), 512, 0, stream>>>(hidden, W1b, Wq);
  span_eval<<<nblk, 256, 0, stream>>>(Wq, sidx, bids, begins, ends, flags,
                                      weights, b1, W2, b2, partials);
  finalize<<<1, 256, 0, stream>>>(partials, nblk, out, nspans);
}